// Round 3
// baseline (1042.507 us; speedup 1.0000x reference)
//
#include <hip/hip_runtime.h>
#include <hip/hip_bf16.h>

typedef __bf16 bf16x8 __attribute__((ext_vector_type(8)));
typedef float f32x4 __attribute__((ext_vector_type(4)));

#define KDIM 512
#define NDIM 1024
#define DDIM 256
#define TDIM 512
#define MDIM 2048
#define NROWS 16384          // B*T type_flat rows
#define NEGV -1e10f

__device__ __forceinline__ unsigned short f2b(float f) {
    unsigned int u = __builtin_bit_cast(unsigned int, f);
    u += 0x7fffu + ((u >> 16) & 1u);   // RNE
    return (unsigned short)(u >> 16);
}
__device__ __forceinline__ float b2f_lo(unsigned int v) {   // low 16 bits -> f32
    return __builtin_bit_cast(float, v << 16);
}
__device__ __forceinline__ float b2f_hi(unsigned int v) {   // high 16 bits -> f32
    return __builtin_bit_cast(float, v & 0xffff0000u);
}

typedef const __attribute__((address_space(1))) unsigned int* gas_p;
typedef __attribute__((address_space(3))) unsigned int* las_p;
__device__ __forceinline__ void gl2lds16(const void* g, void* l) {
    // async global->LDS DMA, 16 B/lane; LDS dest = uniform base + lane*16
    __builtin_amdgcn_global_load_lds((gas_p)g, (las_p)l, 16, 0, 0);
}

// ---------------------------------------------------------------------------
// prep: type_flat (k=0 slices of token_reprs, f32) -> bf16 [16384][256]
// ---------------------------------------------------------------------------
__global__ void prep_tok(const float* __restrict__ tok,
                         unsigned short* __restrict__ tfb) {
    int g = (blockIdx.x * 256 + threadIdx.x) * 4;
    int i = g >> 8;
    int c = g & 255;
    float4 v = *(const float4*)(tok + (size_t)i * 1024 + c);
    tfb[g + 0] = f2b(v.x);
    tfb[g + 1] = f2b(v.y);
    tfb[g + 2] = f2b(v.z);
    tfb[g + 3] = f2b(v.w);
}

// ---------------------------------------------------------------------------
// prep: Wg, Wv f32 [k][n] -> bf16 transposed [n][k], LDS-tiled for coalescing
// ---------------------------------------------------------------------------
__global__ void prep_w(const float* __restrict__ Wg,
                       const float* __restrict__ Wv,
                       unsigned short* __restrict__ wgT,
                       unsigned short* __restrict__ wvT) {
    __shared__ float tg[32][33];
    __shared__ float tv[32][33];
    const int tid = threadIdx.x;
    const int n0 = blockIdx.x * 32, k0 = blockIdx.y * 32;
    {
        int kk = tid >> 3, nn = (tid & 7) * 4;
        float4 g = *(const float4*)(Wg + (size_t)(k0 + kk) * NDIM + n0 + nn);
        float4 v = *(const float4*)(Wv + (size_t)(k0 + kk) * NDIM + n0 + nn);
        tg[kk][nn] = g.x; tg[kk][nn + 1] = g.y; tg[kk][nn + 2] = g.z; tg[kk][nn + 3] = g.w;
        tv[kk][nn] = v.x; tv[kk][nn + 1] = v.y; tv[kk][nn + 2] = v.z; tv[kk][nn + 3] = v.w;
    }
    __syncthreads();
    int nn2 = tid >> 3, kk2 = (tid & 7) * 4;
    unsigned int g0 = f2b(tg[kk2][nn2]) | ((unsigned int)f2b(tg[kk2 + 1][nn2]) << 16);
    unsigned int g1 = f2b(tg[kk2 + 2][nn2]) | ((unsigned int)f2b(tg[kk2 + 3][nn2]) << 16);
    unsigned int v0 = f2b(tv[kk2][nn2]) | ((unsigned int)f2b(tv[kk2 + 1][nn2]) << 16);
    unsigned int v1 = f2b(tv[kk2 + 2][nn2]) | ((unsigned int)f2b(tv[kk2 + 3][nn2]) << 16);
    uint2 gp; gp.x = g0; gp.y = g1;
    uint2 vp; vp.x = v0; vp.y = v1;
    *(uint2*)(wgT + (size_t)(n0 + nn2) * KDIM + k0 + kk2) = gp;
    *(uint2*)(wvT + (size_t)(n0 + nn2) * KDIM + k0 + kk2) = vp;
}

// ---------------------------------------------------------------------------
// lemmas: fused gather + dual GEMM + silu(G)*V @ Wo reduce.
// global_load_lds width-16 staging; XOR-swizzled LDS (no pad, conflict-free
// b128 fragment reads). 128e x 128n tile, BK=64, 4 waves x (64x64), dual acc.
// ---------------------------------------------------------------------------
__launch_bounds__(256, 3)
__global__ void lemma_gemm(const unsigned short* __restrict__ tfb,
                           const unsigned short* __restrict__ wgT,
                           const unsigned short* __restrict__ wvT,
                           const float* __restrict__ Wo,
                           const int* __restrict__ scope,
                           const int* __restrict__ goal,
                           float* __restrict__ outLem,
                           int E) {
    __shared__ unsigned short sA[128 * 64];    // 16 KB, [row][unit g^..]
    __shared__ unsigned short sBg[128 * 64];
    __shared__ unsigned short sBv[128 * 64];
    __shared__ float sRed[256];

    const int tid = threadIdx.x;
    const int lane = tid & 63;
    const int w = tid >> 6;
    const int wm = w & 1;
    const int wn = w >> 1;
    const int col = lane & 15;
    const int q = lane >> 4;
    const int r8 = lane >> 3;      // staging: row-in-chunk
    const int c8 = lane & 7;       // staging: 16B unit in LDS row
    const int g8 = c8 ^ r8;        // XOR swizzle: global 16B unit this lane fetches
    const int etile = blockIdx.x * 128;

    // per-lane gather ids for the 4 A-chunks this wave stages (rows fixed per lane)
    int idS[4], idG[4];
#pragma unroll
    for (int i = 0; i < 4; i++) {
        int row = (i * 4 + w) * 8 + r8;
        int e = etile + row;
        idS[i] = (e < E) ? scope[e] : 0;
        idG[i] = (e < E) ? goal[e] : 0;
    }

    float lem[16];
#pragma unroll
    for (int i = 0; i < 16; i++) lem[i] = 0.f;

    for (int nt = 0; nt < NDIM / 128; nt++) {
        const int n0 = nt * 128;
        f32x4 accG[4][4], accV[4][4];
#pragma unroll
        for (int mi = 0; mi < 4; mi++)
#pragma unroll
            for (int ni = 0; ni < 4; ni++) {
                accG[mi][ni] = (f32x4){0.f, 0.f, 0.f, 0.f};
                accV[mi][ni] = (f32x4){0.f, 0.f, 0.f, 0.f};
            }
        for (int kc = 0; kc < KDIM / 64; kc++) {
            const int k0 = kc * 64;
            const int kmod = k0 & 255;
            const bool useS = (k0 < 256);
            __syncthreads();
#pragma unroll
            for (int i = 0; i < 4; i++) {
                const int chunk = i * 4 + w;
                int id = useS ? idS[i] : idG[i];
                gl2lds16(tfb + (size_t)id * DDIM + kmod + g8 * 8, &sA[chunk * 512]);
                int rowB = chunk * 8 + r8;
                gl2lds16(wgT + (size_t)(n0 + rowB) * KDIM + k0 + g8 * 8, &sBg[chunk * 512]);
                gl2lds16(wvT + (size_t)(n0 + rowB) * KDIM + k0 + g8 * 8, &sBv[chunk * 512]);
            }
            __syncthreads();
#pragma unroll
            for (int kkU = 0; kkU < 8; kkU += 4) {   // 16B-unit offset: kk = kkU*8 elems
                bf16x8 af[4], bg[4], bv[4];
#pragma unroll
                for (int mi = 0; mi < 4; mi++) {
                    int row = wm * 64 + mi * 16 + col;
                    int swz = (q + kkU) ^ c8;        // row&7 == c8
                    af[mi] = __builtin_bit_cast(bf16x8,
                        *(const uint4*)(&sA[row * 64 + swz * 8]));
                }
#pragma unroll
                for (int ni = 0; ni < 4; ni++) {
                    int row = wn * 64 + ni * 16 + col;
                    int swz = (q + kkU) ^ c8;
                    bg[ni] = __builtin_bit_cast(bf16x8,
                        *(const uint4*)(&sBg[row * 64 + swz * 8]));
                    bv[ni] = __builtin_bit_cast(bf16x8,
                        *(const uint4*)(&sBv[row * 64 + swz * 8]));
                }
#pragma unroll
                for (int mi = 0; mi < 4; mi++)
#pragma unroll
                    for (int ni = 0; ni < 4; ni++) {
                        accG[mi][ni] = __builtin_amdgcn_mfma_f32_16x16x32_bf16(
                            af[mi], bg[ni], accG[mi][ni], 0, 0, 0);
                        accV[mi][ni] = __builtin_amdgcn_mfma_f32_16x16x32_bf16(
                            af[mi], bv[ni], accV[mi][ni], 0, 0, 0);
                    }
            }
        }
        // epilogue: lem += silu(G) * V * Wo[n]. C/D: M=q*4+r, N=col (m89).
#pragma unroll
        for (int ni = 0; ni < 4; ni++) {
            float wo = Wo[n0 + wn * 64 + ni * 16 + col];
#pragma unroll
            for (int mi = 0; mi < 4; mi++)
#pragma unroll
                for (int r = 0; r < 4; r++) {
                    float g = accG[mi][ni][r];
                    float v = accV[mi][ni][r];
                    float s = g / (1.f + __expf(-g));
                    lem[mi * 4 + r] += s * v * wo;
                }
        }
    }
    // reduce across the 16 N-cols, then across the 2 n-waves via LDS
#pragma unroll
    for (int i = 0; i < 16; i++) {
        float v = lem[i];
        for (int off = 8; off > 0; off >>= 1) v += __shfl_xor(v, off, 16);
        if (col == 0) {
            int row = wm * 64 + (i >> 2) * 16 + q * 4 + (i & 3);
            sRed[wn * 128 + row] = v;
        }
    }
    __syncthreads();
    if (tid < 128) {
        int e = etile + tid;
        if (e < E) outLem[e] = sRed[tid] + sRed[128 + tid];
    }
}

// ---------------------------------------------------------------------------
// lm_preds grouped by b: block = (b, 128-t chunk). Candidate tile staged once
// in LDS (bf16, [d][t] for conflict-free reads), waves scan bp for their m's.
// Mask row lives in registers, broadcast via __shfl.
// ---------------------------------------------------------------------------
__launch_bounds__(256, 1)
__global__ void lm_preds_grouped(const float* __restrict__ tok,
                                 const unsigned short* __restrict__ tfb,
                                 const int* __restrict__ lmi,
                                 const int* __restrict__ bp,
                                 const int* __restrict__ tpm,
                                 float* __restrict__ outP) {
    __shared__ unsigned short candT[256][128];   // [d][t] bf16 = 64 KB
    const int tid = threadIdx.x;
    const int b = blockIdx.x;
    const int t0 = blockIdx.y * 128;
    // stage candidate tile: rows tfb[b*512 + t0 + t][:] -> candT[d][t]
    {
        int t = tid >> 1, dh = (tid & 1) * 128;
        const unsigned short* src = tfb + ((size_t)(b * TDIM + t0 + t)) * DDIM + dh;
#pragma unroll
        for (int j = 0; j < 16; j++) {
            uint4 u = *(const uint4*)(src + j * 8);
            const unsigned short* s = (const unsigned short*)&u;
#pragma unroll
            for (int k = 0; k < 8; k++) candT[dh + j * 8 + k][t] = s[k];
        }
    }
    __syncthreads();
    const int lane = tid & 63;
    const int w = tid >> 6;
    const int* pm = tpm + b * TDIM;
    const int ta = t0 + lane * 2;
    const float msk0 = pm[ta] ? 1.f : 0.f;       // loaded once per block
    const float msk1 = pm[ta + 1] ? 1.f : 0.f;
    // each wave scans a quarter of the m range for bp[m]==b (uniform branch)
    for (int m = w * (MDIM / 4); m < (w + 1) * (MDIM / 4); m++) {
        if (bp[m] != b) continue;
        float4 mv = *(const float4*)(tok + (size_t)lmi[m] * DDIM + lane * 4);
        float a0 = 0.f, a1 = 0.f;
#pragma unroll 8
        for (int d4 = 0; d4 < 64; d4++) {
            float m0 = __shfl(mv.x, d4);
            float m1 = __shfl(mv.y, d4);
            float m2 = __shfl(mv.z, d4);
            float m3 = __shfl(mv.w, d4);
            unsigned int c0 = *(const unsigned int*)&candT[4 * d4 + 0][lane * 2];
            unsigned int c1 = *(const unsigned int*)&candT[4 * d4 + 1][lane * 2];
            unsigned int c2 = *(const unsigned int*)&candT[4 * d4 + 2][lane * 2];
            unsigned int c3 = *(const unsigned int*)&candT[4 * d4 + 3][lane * 2];
            a0 += m0 * b2f_lo(c0) + m1 * b2f_lo(c1) + m2 * b2f_lo(c2) + m3 * b2f_lo(c3);
            a1 += m0 * b2f_hi(c0) + m1 * b2f_hi(c1) + m2 * b2f_hi(c2) + m3 * b2f_hi(c3);
        }
        float2 r;
        r.x = msk0 != 0.f ? a0 : NEGV;
        r.y = msk1 != 0.f ? a1 : NEGV;
        *(float2*)(outP + (size_t)m * TDIM + ta) = r;
    }
}

extern "C" void kernel_launch(void* const* d_in, const int* in_sizes, int n_in,
                              void* d_out, int out_size, void* d_ws, size_t ws_size,
                              hipStream_t stream) {
    const float* tok = (const float*)d_in[0];
    const float* Wg  = (const float*)d_in[1];
    const float* Wv  = (const float*)d_in[2];
    const float* Wo  = (const float*)d_in[3];
    const int* edge = (const int*)d_in[4];
    const int* lmi  = (const int*)d_in[5];
    const int* bp   = (const int*)d_in[6];
    const int* tpm  = (const int*)d_in[7];
    const int E = in_sizes[4] / 2;           // 100000
    float* out = (float*)d_out;

    unsigned short* tfb = (unsigned short*)d_ws;              // 8 MB
    unsigned short* wgT = tfb + (size_t)NROWS * DDIM;         // 1 MB
    unsigned short* wvT = wgT + (size_t)KDIM * NDIM;          // 1 MB

    prep_tok<<<dim3((NROWS * DDIM) / 1024), dim3(256), 0, stream>>>(tok, tfb);
    prep_w<<<dim3(NDIM / 32, KDIM / 32), dim3(256), 0, stream>>>(Wg, Wv, wgT, wvT);
    lemma_gemm<<<dim3((E + 127) / 128), dim3(256), 0, stream>>>(
        tfb, wgT, wvT, Wo, edge, edge + E, out, E);
    lm_preds_grouped<<<dim3(32, TDIM / 128), dim3(256), 0, stream>>>(
        tok, tfb, lmi, bp, tpm, out + E);
}

// Round 4
// 480.818 us; speedup vs baseline: 2.1682x; 2.1682x over previous
//
#include <hip/hip_runtime.h>
#include <hip/hip_bf16.h>

typedef __bf16 bf16x8 __attribute__((ext_vector_type(8)));
typedef float f32x4 __attribute__((ext_vector_type(4)));
typedef float f32x2 __attribute__((ext_vector_type(2)));

#define KDIM 512
#define NDIM 1024
#define DDIM 256
#define TDIM 512
#define MDIM 2048
#define NROWS 16384          // B*T type_flat rows
#define NEGV -1e10f

__device__ __forceinline__ unsigned short f2b(float f) {
    unsigned int u = __builtin_bit_cast(unsigned int, f);
    u += 0x7fffu + ((u >> 16) & 1u);   // RNE
    return (unsigned short)(u >> 16);
}
__device__ __forceinline__ float b2f_lo(unsigned int v) {
    return __builtin_bit_cast(float, v << 16);
}
__device__ __forceinline__ float b2f_hi(unsigned int v) {
    return __builtin_bit_cast(float, v & 0xffff0000u);
}

typedef const __attribute__((address_space(1))) unsigned int* gas_p;
typedef __attribute__((address_space(3))) unsigned int* las_p;
__device__ __forceinline__ void gl2lds16(const void* g, void* l) {
    // async global->LDS DMA, 16 B/lane; LDS dest = uniform base + lane*16
    __builtin_amdgcn_global_load_lds((gas_p)g, (las_p)l, 16, 0, 0);
}

// ---------------------------------------------------------------------------
// prep: type_flat (k=0 slices of token_reprs, f32) -> bf16 [16384][256]
// ---------------------------------------------------------------------------
__global__ void prep_tok(const float* __restrict__ tok,
                         unsigned short* __restrict__ tfb) {
    int g = (blockIdx.x * 256 + threadIdx.x) * 4;
    int i = g >> 8;
    int c = g & 255;
    float4 v = *(const float4*)(tok + (size_t)i * 1024 + c);
    tfb[g + 0] = f2b(v.x);
    tfb[g + 1] = f2b(v.y);
    tfb[g + 2] = f2b(v.z);
    tfb[g + 3] = f2b(v.w);
}

// ---------------------------------------------------------------------------
// prep: Wg, Wv f32 [k][n] -> bf16 transposed [n][k], LDS-tiled for coalescing
// ---------------------------------------------------------------------------
__global__ void prep_w(const float* __restrict__ Wg,
                       const float* __restrict__ Wv,
                       unsigned short* __restrict__ wgT,
                       unsigned short* __restrict__ wvT) {
    __shared__ float tg[32][33];
    __shared__ float tv[32][33];
    const int tid = threadIdx.x;
    const int n0 = blockIdx.x * 32, k0 = blockIdx.y * 32;
    {
        int kk = tid >> 3, nn = (tid & 7) * 4;
        float4 g = *(const float4*)(Wg + (size_t)(k0 + kk) * NDIM + n0 + nn);
        float4 v = *(const float4*)(Wv + (size_t)(k0 + kk) * NDIM + n0 + nn);
        tg[kk][nn] = g.x; tg[kk][nn + 1] = g.y; tg[kk][nn + 2] = g.z; tg[kk][nn + 3] = g.w;
        tv[kk][nn] = v.x; tv[kk][nn + 1] = v.y; tv[kk][nn + 2] = v.z; tv[kk][nn + 3] = v.w;
    }
    __syncthreads();
    int nn2 = tid >> 3, kk2 = (tid & 7) * 4;
    unsigned int g0 = f2b(tg[kk2][nn2]) | ((unsigned int)f2b(tg[kk2 + 1][nn2]) << 16);
    unsigned int g1 = f2b(tg[kk2 + 2][nn2]) | ((unsigned int)f2b(tg[kk2 + 3][nn2]) << 16);
    unsigned int v0 = f2b(tv[kk2][nn2]) | ((unsigned int)f2b(tv[kk2 + 1][nn2]) << 16);
    unsigned int v1 = f2b(tv[kk2 + 2][nn2]) | ((unsigned int)f2b(tv[kk2 + 3][nn2]) << 16);
    uint2 gp; gp.x = g0; gp.y = g1;
    uint2 vp; vp.x = v0; vp.y = v1;
    *(uint2*)(wgT + (size_t)(n0 + nn2) * KDIM + k0 + kk2) = gp;
    *(uint2*)(wvT + (size_t)(n0 + nn2) * KDIM + k0 + kk2) = vp;
}

// ---------------------------------------------------------------------------
// lemmas: fused gather + dual GEMM + silu(G)*V @ Wo reduce.
// global_load_lds width-16 staging; XOR-swizzled LDS (conflict-free b128).
// 128e x 128n tile, BK=64, 4 waves x (64x64), dual acc (128 AGPRs).
// __launch_bounds__(256,2): 2 blocks/CU. (256,3) caps unified VGPR budget at
// ~170 and SPILLS the 128-reg accumulator -> 1.3 GB scratch traffic (round 3).
// ---------------------------------------------------------------------------
__launch_bounds__(256, 2)
__global__ void lemma_gemm(const unsigned short* __restrict__ tfb,
                           const unsigned short* __restrict__ wgT,
                           const unsigned short* __restrict__ wvT,
                           const float* __restrict__ Wo,
                           const int* __restrict__ scope,
                           const int* __restrict__ goal,
                           float* __restrict__ outLem,
                           int E) {
    __shared__ unsigned short sA[128 * 64];    // 16 KB, [row][swizzled 16B unit]
    __shared__ unsigned short sBg[128 * 64];
    __shared__ unsigned short sBv[128 * 64];
    __shared__ float sRed[256];

    const int tid = threadIdx.x;
    const int lane = tid & 63;
    const int w = tid >> 6;
    const int wm = w & 1;
    const int wn = w >> 1;
    const int col = lane & 15;
    const int q = lane >> 4;
    const int r8 = lane >> 3;      // staging: row-in-chunk
    const int c8 = lane & 7;       // staging: 16B unit in LDS row
    const int g8 = c8 ^ r8;        // XOR swizzle: global 16B unit this lane fetches
    const int etile = blockIdx.x * 128;

    int idS[4], idG[4];
#pragma unroll
    for (int i = 0; i < 4; i++) {
        int row = (i * 4 + w) * 8 + r8;
        int e = etile + row;
        idS[i] = (e < E) ? scope[e] : 0;
        idG[i] = (e < E) ? goal[e] : 0;
    }

    float lem[16];
#pragma unroll
    for (int i = 0; i < 16; i++) lem[i] = 0.f;

    for (int nt = 0; nt < NDIM / 128; nt++) {
        const int n0 = nt * 128;
        f32x4 accG[4][4], accV[4][4];
#pragma unroll
        for (int mi = 0; mi < 4; mi++)
#pragma unroll
            for (int ni = 0; ni < 4; ni++) {
                accG[mi][ni] = (f32x4){0.f, 0.f, 0.f, 0.f};
                accV[mi][ni] = (f32x4){0.f, 0.f, 0.f, 0.f};
            }
        for (int kc = 0; kc < KDIM / 64; kc++) {
            const int k0 = kc * 64;
            const int kmod = k0 & 255;
            const bool useS = (k0 < 256);
            __syncthreads();
#pragma unroll
            for (int i = 0; i < 4; i++) {
                const int chunk = i * 4 + w;
                int id = useS ? idS[i] : idG[i];
                gl2lds16(tfb + (size_t)id * DDIM + kmod + g8 * 8, &sA[chunk * 512]);
                int rowB = chunk * 8 + r8;
                gl2lds16(wgT + (size_t)(n0 + rowB) * KDIM + k0 + g8 * 8, &sBg[chunk * 512]);
                gl2lds16(wvT + (size_t)(n0 + rowB) * KDIM + k0 + g8 * 8, &sBv[chunk * 512]);
            }
            __syncthreads();
#pragma unroll
            for (int kkU = 0; kkU < 8; kkU += 4) {
                bf16x8 af[4], bg[4], bv[4];
#pragma unroll
                for (int mi = 0; mi < 4; mi++) {
                    int row = wm * 64 + mi * 16 + col;
                    int swz = (q + kkU) ^ c8;        // row&7 == c8
                    af[mi] = __builtin_bit_cast(bf16x8,
                        *(const uint4*)(&sA[row * 64 + swz * 8]));
                }
#pragma unroll
                for (int ni = 0; ni < 4; ni++) {
                    int row = wn * 64 + ni * 16 + col;
                    int swz = (q + kkU) ^ c8;
                    bg[ni] = __builtin_bit_cast(bf16x8,
                        *(const uint4*)(&sBg[row * 64 + swz * 8]));
                    bv[ni] = __builtin_bit_cast(bf16x8,
                        *(const uint4*)(&sBv[row * 64 + swz * 8]));
                }
#pragma unroll
                for (int mi = 0; mi < 4; mi++)
#pragma unroll
                    for (int ni = 0; ni < 4; ni++) {
                        accG[mi][ni] = __builtin_amdgcn_mfma_f32_16x16x32_bf16(
                            af[mi], bg[ni], accG[mi][ni], 0, 0, 0);
                        accV[mi][ni] = __builtin_amdgcn_mfma_f32_16x16x32_bf16(
                            af[mi], bv[ni], accV[mi][ni], 0, 0, 0);
                    }
            }
        }
        // epilogue: lem += silu(G) * V * Wo[n]. C/D: M=q*4+r, N=col (m89).
#pragma unroll
        for (int ni = 0; ni < 4; ni++) {
            float wo = Wo[n0 + wn * 64 + ni * 16 + col];
#pragma unroll
            for (int mi = 0; mi < 4; mi++)
#pragma unroll
                for (int r = 0; r < 4; r++) {
                    float g = accG[mi][ni][r];
                    float v = accV[mi][ni][r];
                    float s = g / (1.f + __expf(-g));
                    lem[mi * 4 + r] += s * v * wo;
                }
        }
    }
#pragma unroll
    for (int i = 0; i < 16; i++) {
        float v = lem[i];
        for (int off = 8; off > 0; off >>= 1) v += __shfl_xor(v, off, 16);
        if (col == 0) {
            int row = wm * 64 + (i >> 2) * 16 + q * 4 + (i & 3);
            sRed[wn * 128 + row] = v;
        }
    }
    __syncthreads();
    if (tid < 128) {
        int e = etile + tid;
        if (e < E) outLem[e] = sRed[tid] + sRed[128 + tid];
    }
}

// ---------------------------------------------------------------------------
// lm_preds grouped by b: block = (b, 128-t chunk). Candidate tile staged once
// in LDS transposed [d][t]; bp staged in LDS + ballot match-scan (kills the
// 512-deep serial s_load chain of round 3); float2 packed fma inner loop.
// ---------------------------------------------------------------------------
__launch_bounds__(256, 2)
__global__ void lm_preds_grouped(const float* __restrict__ tok,
                                 const unsigned short* __restrict__ tfb,
                                 const int* __restrict__ lmi,
                                 const int* __restrict__ bp,
                                 const int* __restrict__ tpm,
                                 float* __restrict__ outP) {
    __shared__ unsigned short candT[256][128];   // [d][t] bf16 = 64 KB
    __shared__ int sBp[MDIM];                    // 8 KB
    const int tid = threadIdx.x;
    const int b = blockIdx.x;
    const int t0 = blockIdx.y * 128;
    {
        int4* dst = (int4*)sBp;
        const int4* src = (const int4*)bp;
        dst[tid] = src[tid];
        dst[256 + tid] = src[256 + tid];
    }
    {
        int t = tid >> 1, dh = (tid & 1) * 128;
        const unsigned short* src = tfb + ((size_t)(b * TDIM + t0 + t)) * DDIM + dh;
#pragma unroll
        for (int j = 0; j < 16; j++) {
            uint4 u = *(const uint4*)(src + j * 8);
            const unsigned short* s = (const unsigned short*)&u;
#pragma unroll
            for (int k = 0; k < 8; k++) candT[dh + j * 8 + k][t] = s[k];
        }
    }
    __syncthreads();
    const int lane = tid & 63;
    const int w = tid >> 6;
    const int* pm = tpm + b * TDIM;
    const int ta = t0 + lane * 2;
    const bool k0 = pm[ta] != 0;
    const bool k1 = pm[ta + 1] != 0;
    for (int base = w * (MDIM / 4); base < (w + 1) * (MDIM / 4); base += 64) {
        unsigned long long match = __ballot(sBp[base + lane] == b);
        while (match) {
            int bit = __builtin_ctzll(match);
            match &= match - 1;
            int m = base + bit;
            float4 mv = *(const float4*)(tok + (size_t)lmi[m] * DDIM + lane * 4);
            f32x2 acc = (f32x2){0.f, 0.f};
#pragma unroll 8
            for (int d4 = 0; d4 < 64; d4++) {
                float m0 = __shfl(mv.x, d4);
                float m1 = __shfl(mv.y, d4);
                float m2 = __shfl(mv.z, d4);
                float m3 = __shfl(mv.w, d4);
                unsigned int c0 = *(const unsigned int*)&candT[4 * d4 + 0][lane * 2];
                unsigned int c1 = *(const unsigned int*)&candT[4 * d4 + 1][lane * 2];
                unsigned int c2 = *(const unsigned int*)&candT[4 * d4 + 2][lane * 2];
                unsigned int c3 = *(const unsigned int*)&candT[4 * d4 + 3][lane * 2];
                acc += (f32x2){m0, m0} * (f32x2){b2f_lo(c0), b2f_hi(c0)};
                acc += (f32x2){m1, m1} * (f32x2){b2f_lo(c1), b2f_hi(c1)};
                acc += (f32x2){m2, m2} * (f32x2){b2f_lo(c2), b2f_hi(c2)};
                acc += (f32x2){m3, m3} * (f32x2){b2f_lo(c3), b2f_hi(c3)};
            }
            float2 r;
            r.x = k0 ? acc[0] : NEGV;
            r.y = k1 ? acc[1] : NEGV;
            *(float2*)(outP + (size_t)m * TDIM + ta) = r;
        }
    }
}

extern "C" void kernel_launch(void* const* d_in, const int* in_sizes, int n_in,
                              void* d_out, int out_size, void* d_ws, size_t ws_size,
                              hipStream_t stream) {
    const float* tok = (const float*)d_in[0];
    const float* Wg  = (const float*)d_in[1];
    const float* Wv  = (const float*)d_in[2];
    const float* Wo  = (const float*)d_in[3];
    const int* edge = (const int*)d_in[4];
    const int* lmi  = (const int*)d_in[5];
    const int* bp   = (const int*)d_in[6];
    const int* tpm  = (const int*)d_in[7];
    const int E = in_sizes[4] / 2;           // 100000
    float* out = (float*)d_out;

    unsigned short* tfb = (unsigned short*)d_ws;              // 8 MB
    unsigned short* wgT = tfb + (size_t)NROWS * DDIM;         // 1 MB
    unsigned short* wvT = wgT + (size_t)KDIM * NDIM;          // 1 MB

    prep_tok<<<dim3((NROWS * DDIM) / 1024), dim3(256), 0, stream>>>(tok, tfb);
    prep_w<<<dim3(NDIM / 32, KDIM / 32), dim3(256), 0, stream>>>(Wg, Wv, wgT, wvT);
    lemma_gemm<<<dim3((E + 127) / 128), dim3(256), 0, stream>>>(
        tfb, wgT, wvT, Wo, edge, edge + E, out, E);
    lm_preds_grouped<<<dim3(32, TDIM / 128), dim3(256), 0, stream>>>(
        tok, tfb, lmi, bp, tpm, out + E);
}

// Round 5
// 416.172 us; speedup vs baseline: 2.5050x; 1.1553x over previous
//
#include <hip/hip_runtime.h>
#include <hip/hip_bf16.h>

typedef __bf16 bf16x8 __attribute__((ext_vector_type(8)));
typedef float f32x4 __attribute__((ext_vector_type(4)));

#define KDIM 512
#define NDIM 1024
#define DDIM 256
#define TDIM 512
#define MDIM 2048
#define NROWS 16384          // B*T type_flat rows
#define NEGV -1e10f

__device__ __forceinline__ unsigned short f2b(float f) {
    unsigned int u = __builtin_bit_cast(unsigned int, f);
    u += 0x7fffu + ((u >> 16) & 1u);   // RNE
    return (unsigned short)(u >> 16);
}

typedef const __attribute__((address_space(1))) unsigned int* gas_p;
typedef __attribute__((address_space(3))) unsigned int* las_p;
__device__ __forceinline__ void gl2lds16(const void* g, void* l) {
    // async global->LDS DMA, 16 B/lane; LDS dest = uniform base + lane*16
    __builtin_amdgcn_global_load_lds((gas_p)g, (las_p)l, 16, 0, 0);
}

// ---------------------------------------------------------------------------
// prep: type_flat (k=0 slices of token_reprs, f32) -> bf16 [16384][256]
// ---------------------------------------------------------------------------
__global__ void prep_tok(const float* __restrict__ tok,
                         unsigned short* __restrict__ tfb) {
    int g = (blockIdx.x * 256 + threadIdx.x) * 4;
    int i = g >> 8;
    int c = g & 255;
    float4 v = *(const float4*)(tok + (size_t)i * 1024 + c);
    tfb[g + 0] = f2b(v.x);
    tfb[g + 1] = f2b(v.y);
    tfb[g + 2] = f2b(v.z);
    tfb[g + 3] = f2b(v.w);
}

// ---------------------------------------------------------------------------
// prep: Wg, Wv f32 [k][n] -> bf16 transposed [n][k], LDS-tiled for coalescing
// ---------------------------------------------------------------------------
__global__ void prep_w(const float* __restrict__ Wg,
                       const float* __restrict__ Wv,
                       unsigned short* __restrict__ wgT,
                       unsigned short* __restrict__ wvT) {
    __shared__ float tg[32][33];
    __shared__ float tv[32][33];
    const int tid = threadIdx.x;
    const int n0 = blockIdx.x * 32, k0 = blockIdx.y * 32;
    {
        int kk = tid >> 3, nn = (tid & 7) * 4;
        float4 g = *(const float4*)(Wg + (size_t)(k0 + kk) * NDIM + n0 + nn);
        float4 v = *(const float4*)(Wv + (size_t)(k0 + kk) * NDIM + n0 + nn);
        tg[kk][nn] = g.x; tg[kk][nn + 1] = g.y; tg[kk][nn + 2] = g.z; tg[kk][nn + 3] = g.w;
        tv[kk][nn] = v.x; tv[kk][nn + 1] = v.y; tv[kk][nn + 2] = v.z; tv[kk][nn + 3] = v.w;
    }
    __syncthreads();
    int nn2 = tid >> 3, kk2 = (tid & 7) * 4;
    unsigned int g0 = f2b(tg[kk2][nn2]) | ((unsigned int)f2b(tg[kk2 + 1][nn2]) << 16);
    unsigned int g1 = f2b(tg[kk2 + 2][nn2]) | ((unsigned int)f2b(tg[kk2 + 3][nn2]) << 16);
    unsigned int v0 = f2b(tv[kk2][nn2]) | ((unsigned int)f2b(tv[kk2 + 1][nn2]) << 16);
    unsigned int v1 = f2b(tv[kk2 + 2][nn2]) | ((unsigned int)f2b(tv[kk2 + 3][nn2]) << 16);
    uint2 gp; gp.x = g0; gp.y = g1;
    uint2 vp; vp.x = v0; vp.y = v1;
    *(uint2*)(wgT + (size_t)(n0 + nn2) * KDIM + k0 + kk2) = gp;
    *(uint2*)(wvT + (size_t)(n0 + nn2) * KDIM + k0 + kk2) = vp;
}

// ---------------------------------------------------------------------------
// prep_lists: bucket m-indices by batch pointer. counts/lists live in the
// LEMMA OUTPUT region (overwritten later by lemma_gemm; lm_gemm reads them
// first — stream order guarantees safety). 1 block.
// ---------------------------------------------------------------------------
__global__ void prep_lists(const int* __restrict__ bp,
                           int* __restrict__ counts,            // [32]
                           unsigned short* __restrict__ lists)  // [32][2048]
{
    __shared__ int c[32];
    const int tid = threadIdx.x;
    if (tid < 32) c[tid] = 0;
    __syncthreads();
    for (int m = tid; m < MDIM; m += 256) {
        int b = bp[m];
        int pos = atomicAdd(&c[b], 1);
        lists[b * MDIM + pos] = (unsigned short)m;
    }
    __syncthreads();
    if (tid < 32) counts[tid] = c[tid];
}

// ---------------------------------------------------------------------------
// lemmas: fused gather + dual GEMM + silu(G)*V @ Wo reduce. (unchanged R4)
// global_load_lds width-16 staging; XOR-swizzled LDS (conflict-free b128).
// 128e x 128n tile, BK=64, 4 waves x (64x64), dual acc (128 AGPRs).
// (256,2): (256,3) caps unified VGPRs ~170 and spills the accumulator (R3).
// ---------------------------------------------------------------------------
__launch_bounds__(256, 2)
__global__ void lemma_gemm(const unsigned short* __restrict__ tfb,
                           const unsigned short* __restrict__ wgT,
                           const unsigned short* __restrict__ wvT,
                           const float* __restrict__ Wo,
                           const int* __restrict__ scope,
                           const int* __restrict__ goal,
                           float* __restrict__ outLem,
                           int E) {
    __shared__ unsigned short sA[128 * 64];    // 16 KB, [row][swizzled 16B unit]
    __shared__ unsigned short sBg[128 * 64];
    __shared__ unsigned short sBv[128 * 64];
    __shared__ float sRed[256];

    const int tid = threadIdx.x;
    const int lane = tid & 63;
    const int w = tid >> 6;
    const int wm = w & 1;
    const int wn = w >> 1;
    const int col = lane & 15;
    const int q = lane >> 4;
    const int r8 = lane >> 3;
    const int c8 = lane & 7;
    const int g8 = c8 ^ r8;        // XOR swizzle
    const int etile = blockIdx.x * 128;

    int idS[4], idG[4];
#pragma unroll
    for (int i = 0; i < 4; i++) {
        int row = (i * 4 + w) * 8 + r8;
        int e = etile + row;
        idS[i] = (e < E) ? scope[e] : 0;
        idG[i] = (e < E) ? goal[e] : 0;
    }

    float lem[16];
#pragma unroll
    for (int i = 0; i < 16; i++) lem[i] = 0.f;

    for (int nt = 0; nt < NDIM / 128; nt++) {
        const int n0 = nt * 128;
        f32x4 accG[4][4], accV[4][4];
#pragma unroll
        for (int mi = 0; mi < 4; mi++)
#pragma unroll
            for (int ni = 0; ni < 4; ni++) {
                accG[mi][ni] = (f32x4){0.f, 0.f, 0.f, 0.f};
                accV[mi][ni] = (f32x4){0.f, 0.f, 0.f, 0.f};
            }
        for (int kc = 0; kc < KDIM / 64; kc++) {
            const int k0 = kc * 64;
            const int kmod = k0 & 255;
            const bool useS = (k0 < 256);
            __syncthreads();
#pragma unroll
            for (int i = 0; i < 4; i++) {
                const int chunk = i * 4 + w;
                int id = useS ? idS[i] : idG[i];
                gl2lds16(tfb + (size_t)id * DDIM + kmod + g8 * 8, &sA[chunk * 512]);
                int rowB = chunk * 8 + r8;
                gl2lds16(wgT + (size_t)(n0 + rowB) * KDIM + k0 + g8 * 8, &sBg[chunk * 512]);
                gl2lds16(wvT + (size_t)(n0 + rowB) * KDIM + k0 + g8 * 8, &sBv[chunk * 512]);
            }
            __syncthreads();
#pragma unroll
            for (int kkU = 0; kkU < 8; kkU += 4) {
                bf16x8 af[4], bg[4], bv[4];
#pragma unroll
                for (int mi = 0; mi < 4; mi++) {
                    int row = wm * 64 + mi * 16 + col;
                    int swz = (q + kkU) ^ c8;
                    af[mi] = __builtin_bit_cast(bf16x8,
                        *(const uint4*)(&sA[row * 64 + swz * 8]));
                }
#pragma unroll
                for (int ni = 0; ni < 4; ni++) {
                    int row = wn * 64 + ni * 16 + col;
                    int swz = (q + kkU) ^ c8;
                    bg[ni] = __builtin_bit_cast(bf16x8,
                        *(const uint4*)(&sBg[row * 64 + swz * 8]));
                    bv[ni] = __builtin_bit_cast(bf16x8,
                        *(const uint4*)(&sBv[row * 64 + swz * 8]));
                }
#pragma unroll
                for (int mi = 0; mi < 4; mi++)
#pragma unroll
                    for (int ni = 0; ni < 4; ni++) {
                        accG[mi][ni] = __builtin_amdgcn_mfma_f32_16x16x32_bf16(
                            af[mi], bg[ni], accG[mi][ni], 0, 0, 0);
                        accV[mi][ni] = __builtin_amdgcn_mfma_f32_16x16x32_bf16(
                            af[mi], bv[ni], accV[mi][ni], 0, 0, 0);
                    }
            }
        }
#pragma unroll
        for (int ni = 0; ni < 4; ni++) {
            float wo = Wo[n0 + wn * 64 + ni * 16 + col];
#pragma unroll
            for (int mi = 0; mi < 4; mi++)
#pragma unroll
                for (int r = 0; r < 4; r++) {
                    float g = accG[mi][ni][r];
                    float v = accV[mi][ni][r];
                    float s = g / (1.f + __expf(-g));
                    lem[mi * 4 + r] += s * v * wo;
                }
        }
    }
#pragma unroll
    for (int i = 0; i < 16; i++) {
        float v = lem[i];
        for (int off = 8; off > 0; off >>= 1) v += __shfl_xor(v, off, 16);
        if (col == 0) {
            int row = wm * 64 + (i >> 2) * 16 + q * 4 + (i & 3);
            sRed[wn * 128 + row] = v;
        }
    }
    __syncthreads();
    if (tid < 128) {
        int e = etile + tid;
        if (e < E) outLem[e] = sRed[tid] + sRed[128 + tid];
    }
}

// ---------------------------------------------------------------------------
// lm_preds as gather-GEMM: block = (b, 128-t chunk), 4 waves. Wave w handles
// m-tiles w, w+4, ... of this b's list. A = mask rows (f32 -> bf16 on the fly),
// B = tfb rows (already [t][d], direct b128 loads, L2-hot). 16x16x32 MFMA,
// masked scattered f32 stores. No LDS, no barriers.
// ---------------------------------------------------------------------------
__global__ void lm_gemm(const float* __restrict__ tok,
                        const unsigned short* __restrict__ tfb,
                        const int* __restrict__ lmi,
                        const int* __restrict__ counts,
                        const unsigned short* __restrict__ lists,
                        const int* __restrict__ tpm,
                        float* __restrict__ outP) {
    const int b = blockIdx.x;
    const int t0 = blockIdx.y * 128;
    const int cnt = counts[b];
    const int tid = threadIdx.x;
    const int lane = tid & 63;
    const int w = tid >> 6;
    const int col = lane & 15;
    const int q = lane >> 4;

    for (int mt = w * 16; mt < cnt; mt += 64) {
        // A-row id for this lane's col (clamped; rows >= cnt produce garbage
        // in D rows >= cnt which are never written)
        int mc = mt + col;
        int aid = lists[b * MDIM + (mc < cnt ? mc : cnt - 1)];
        const float* arow = tok + (size_t)lmi[aid] * DDIM;
        bf16x8 af[8];
#pragma unroll
        for (int k = 0; k < 8; k++) {
            float4 lo = *(const float4*)(arow + k * 32 + q * 8);
            float4 hi = *(const float4*)(arow + k * 32 + q * 8 + 4);
            uint4 p;
            p.x = f2b(lo.x) | ((unsigned int)f2b(lo.y) << 16);
            p.y = f2b(lo.z) | ((unsigned int)f2b(lo.w) << 16);
            p.z = f2b(hi.x) | ((unsigned int)f2b(hi.y) << 16);
            p.w = f2b(hi.z) | ((unsigned int)f2b(hi.w) << 16);
            af[k] = __builtin_bit_cast(bf16x8, p);
        }
        // output row ids for this lane's 4 accumulator rows
        int gm[4];
#pragma unroll
        for (int r = 0; r < 4; r++) {
            int mrow = mt + q * 4 + r;
            gm[r] = (mrow < cnt) ? (int)lists[b * MDIM + mrow] : -1;
        }
#pragma unroll
        for (int ntile = 0; ntile < 8; ntile++) {
            int t = t0 + ntile * 16 + col;
            const unsigned short* brow = tfb + (size_t)(b * TDIM + t) * DDIM;
            f32x4 acc = (f32x4){0.f, 0.f, 0.f, 0.f};
#pragma unroll
            for (int k = 0; k < 8; k++) {
                bf16x8 bf = __builtin_bit_cast(bf16x8,
                    *(const uint4*)(brow + k * 32 + q * 8));
                acc = __builtin_amdgcn_mfma_f32_16x16x32_bf16(af[k], bf, acc, 0, 0, 0);
            }
            int pmv = tpm[b * TDIM + t];
#pragma unroll
            for (int r = 0; r < 4; r++) {
                if (gm[r] >= 0)
                    outP[(size_t)gm[r] * TDIM + t] = pmv ? acc[r] : NEGV;
            }
        }
    }
}

extern "C" void kernel_launch(void* const* d_in, const int* in_sizes, int n_in,
                              void* d_out, int out_size, void* d_ws, size_t ws_size,
                              hipStream_t stream) {
    const float* tok = (const float*)d_in[0];
    const float* Wg  = (const float*)d_in[1];
    const float* Wv  = (const float*)d_in[2];
    const float* Wo  = (const float*)d_in[3];
    const int* edge = (const int*)d_in[4];
    const int* lmi  = (const int*)d_in[5];
    const int* bp   = (const int*)d_in[6];
    const int* tpm  = (const int*)d_in[7];
    const int E = in_sizes[4] / 2;           // 100000
    float* out = (float*)d_out;

    unsigned short* tfb = (unsigned short*)d_ws;              // 8 MB
    unsigned short* wgT = tfb + (size_t)NROWS * DDIM;         // 1 MB
    unsigned short* wvT = wgT + (size_t)KDIM * NDIM;          // 1 MB

    // counts+lists live in the lemmas output region (400 KB): written by
    // prep_lists, consumed by lm_gemm, then OVERWRITTEN by lemma_gemm.
    int* counts = (int*)d_out;                                 // 128 B
    unsigned short* lists = (unsigned short*)(counts + 32);    // 128 KB

    prep_tok<<<dim3((NROWS * DDIM) / 1024), dim3(256), 0, stream>>>(tok, tfb);
    prep_w<<<dim3(NDIM / 32, KDIM / 32), dim3(256), 0, stream>>>(Wg, Wv, wgT, wvT);
    prep_lists<<<dim3(1), dim3(256), 0, stream>>>(bp, counts, lists);
    lm_gemm<<<dim3(32, TDIM / 128), dim3(256), 0, stream>>>(
        tok, tfb, lmi, counts, lists, tpm, out + E);
    lemma_gemm<<<dim3((E + 127) / 128), dim3(256), 0, stream>>>(
        tfb, wgT, wvT, Wo, edge, edge + E, out, E);
}

// Round 6
// 370.052 us; speedup vs baseline: 2.8172x; 1.1246x over previous
//
#include <hip/hip_runtime.h>
#include <hip/hip_bf16.h>

typedef __bf16 bf16x8 __attribute__((ext_vector_type(8)));
typedef int   i32x8 __attribute__((ext_vector_type(8)));
typedef float f32x4 __attribute__((ext_vector_type(4)));

#define KDIM 512
#define NDIM 1024
#define DDIM 256
#define TDIM 512
#define MDIM 2048
#define NROWS 16384          // B*T type_flat rows
#define NEGV -1e10f
#define NLM 128              // lm blocks fused at the front of the main grid

__device__ __forceinline__ unsigned short f2b(float f) {
    unsigned int u = __builtin_bit_cast(unsigned int, f);
    u += 0x7fffu + ((u >> 16) & 1u);   // RNE
    return (unsigned short)(u >> 16);
}

typedef const __attribute__((address_space(1))) unsigned int* gas_p;
typedef __attribute__((address_space(3))) unsigned int* las_p;
__device__ __forceinline__ void gl2lds16(const void* g, void* l) {
    __builtin_amdgcn_global_load_lds((gas_p)g, (las_p)l, 16, 0, 0);
}

// ---------------------------------------------------------------------------
// prep_all: one launch, three roles by blockIdx.
//  blocks [0,4096):    type_flat -> bf16 tfb  AND fp8 tf8
//  blocks [4096,4608): Wg,Wv f32 [k][n] -> fp8 transposed [n][k]
//  block  4608:        bucket m by bp[m] -> counts/lists (in d_ws)
// ---------------------------------------------------------------------------
__global__ void prep_all(const float* __restrict__ tok,
                         const float* __restrict__ Wg,
                         const float* __restrict__ Wv,
                         const int* __restrict__ bp,
                         unsigned short* __restrict__ tfb,
                         unsigned char* __restrict__ tf8,
                         unsigned char* __restrict__ wg8,
                         unsigned char* __restrict__ wv8,
                         int* __restrict__ counts,
                         unsigned short* __restrict__ lists) {
    const int bid = blockIdx.x;
    const int tid = threadIdx.x;
    if (bid < 4096) {
        int g = (bid * 256 + tid) * 4;
        int i = g >> 8, c = g & 255;
        float4 v = *(const float4*)(tok + (size_t)i * 1024 + c);
        tfb[g + 0] = f2b(v.x);
        tfb[g + 1] = f2b(v.y);
        tfb[g + 2] = f2b(v.z);
        tfb[g + 3] = f2b(v.w);
        unsigned int p = (unsigned int)__builtin_amdgcn_cvt_pk_fp8_f32(v.x, v.y, 0, 0);
        p = (unsigned int)__builtin_amdgcn_cvt_pk_fp8_f32(v.z, v.w, (int)p, 1);
        *(unsigned int*)(tf8 + g) = p;
    } else if (bid < 4608) {
        __shared__ float tg[32][33];
        __shared__ float tv[32][33];
        int pb = bid - 4096;
        int n0 = (pb & 31) * 32, k0 = (pb >> 5) * 32;
        {
            int kk = tid >> 3, nn = (tid & 7) * 4;
            float4 g = *(const float4*)(Wg + (size_t)(k0 + kk) * NDIM + n0 + nn);
            float4 v = *(const float4*)(Wv + (size_t)(k0 + kk) * NDIM + n0 + nn);
            tg[kk][nn] = g.x; tg[kk][nn + 1] = g.y; tg[kk][nn + 2] = g.z; tg[kk][nn + 3] = g.w;
            tv[kk][nn] = v.x; tv[kk][nn + 1] = v.y; tv[kk][nn + 2] = v.z; tv[kk][nn + 3] = v.w;
        }
        __syncthreads();
        int nn2 = tid >> 3, kk2 = (tid & 7) * 4;
        unsigned int pg = (unsigned int)__builtin_amdgcn_cvt_pk_fp8_f32(
            tg[kk2][nn2], tg[kk2 + 1][nn2], 0, 0);
        pg = (unsigned int)__builtin_amdgcn_cvt_pk_fp8_f32(
            tg[kk2 + 2][nn2], tg[kk2 + 3][nn2], (int)pg, 1);
        unsigned int pv = (unsigned int)__builtin_amdgcn_cvt_pk_fp8_f32(
            tv[kk2][nn2], tv[kk2 + 1][nn2], 0, 0);
        pv = (unsigned int)__builtin_amdgcn_cvt_pk_fp8_f32(
            tv[kk2 + 2][nn2], tv[kk2 + 3][nn2], (int)pv, 1);
        *(unsigned int*)(wg8 + (size_t)(n0 + nn2) * KDIM + k0 + kk2) = pg;
        *(unsigned int*)(wv8 + (size_t)(n0 + nn2) * KDIM + k0 + kk2) = pv;
    } else {
        __shared__ int c[32];
        if (tid < 32) c[tid] = 0;
        __syncthreads();
        for (int m = tid; m < MDIM; m += 256) {
            int b = bp[m];
            int pos = atomicAdd(&c[b], 1);
            lists[b * MDIM + pos] = (unsigned short)m;
        }
        __syncthreads();
        if (tid < 32) counts[tid] = c[tid];
    }
}

// ---------------------------------------------------------------------------
// fused_main: blocks [0,NLM) = lm_preds gather-GEMM (bf16 MFMA, no LDS);
// blocks [NLM, NLM+782) = lemma MX-fp8 dual GEMM + silu*V@Wo reduce.
// Lemma: K=512 in 4 chunks of 128; one mfma_scale_f32_16x16x128_f8f6f4 (unit
// scales 0x7F = 2^0) per 16x16 tile per chunk. C/D layout is shape-determined
// (m121-128) so the epilogue/reduction is identical to the bf16 version.
// XOR-swizzled LDS at 16B-unit granularity; global_load_lds width-16 staging.
// ---------------------------------------------------------------------------
__launch_bounds__(256, 2)
__global__ void fused_main(const unsigned char* __restrict__ tf8,
                           const unsigned char* __restrict__ wg8,
                           const unsigned char* __restrict__ wv8,
                           const float* __restrict__ Wo,
                           const int* __restrict__ scope,
                           const int* __restrict__ goal,
                           float* __restrict__ outLem, int E,
                           const float* __restrict__ tok,
                           const unsigned short* __restrict__ tfb,
                           const int* __restrict__ lmi,
                           const int* __restrict__ counts,
                           const unsigned short* __restrict__ lists,
                           const int* __restrict__ tpm,
                           float* __restrict__ outP) {
    const int tid = threadIdx.x;
    const int lane = tid & 63;
    const int w = tid >> 6;
    const int col = lane & 15;
    const int q = lane >> 4;

    if ((int)blockIdx.x < NLM) {
        // ---------------- lm_preds gather-GEMM (R5-proven) ----------------
        const int lb = blockIdx.x;
        const int b = lb & 31;
        const int t0 = (lb >> 5) * 128;
        const int cnt = counts[b];
        for (int mt = w * 16; mt < cnt; mt += 64) {
            int mc = mt + col;
            int aid = lists[b * MDIM + (mc < cnt ? mc : cnt - 1)];
            const float* arow = tok + (size_t)lmi[aid] * DDIM;
            bf16x8 af[8];
#pragma unroll
            for (int k = 0; k < 8; k++) {
                float4 lo = *(const float4*)(arow + k * 32 + q * 8);
                float4 hi = *(const float4*)(arow + k * 32 + q * 8 + 4);
                uint4 p;
                p.x = f2b(lo.x) | ((unsigned int)f2b(lo.y) << 16);
                p.y = f2b(lo.z) | ((unsigned int)f2b(lo.w) << 16);
                p.z = f2b(hi.x) | ((unsigned int)f2b(hi.y) << 16);
                p.w = f2b(hi.z) | ((unsigned int)f2b(hi.w) << 16);
                af[k] = __builtin_bit_cast(bf16x8, p);
            }
            int gm[4];
#pragma unroll
            for (int r = 0; r < 4; r++) {
                int mrow = mt + q * 4 + r;
                gm[r] = (mrow < cnt) ? (int)lists[b * MDIM + mrow] : -1;
            }
#pragma unroll
            for (int ntile = 0; ntile < 8; ntile++) {
                int t = t0 + ntile * 16 + col;
                const unsigned short* brow = tfb + (size_t)(b * TDIM + t) * DDIM;
                f32x4 acc = (f32x4){0.f, 0.f, 0.f, 0.f};
#pragma unroll
                for (int k = 0; k < 8; k++) {
                    bf16x8 bf = __builtin_bit_cast(bf16x8,
                        *(const uint4*)(brow + k * 32 + q * 8));
                    acc = __builtin_amdgcn_mfma_f32_16x16x32_bf16(af[k], bf, acc, 0, 0, 0);
                }
                int pmv = tpm[b * TDIM + t];
#pragma unroll
                for (int r = 0; r < 4; r++) {
                    if (gm[r] >= 0)
                        outP[(size_t)gm[r] * TDIM + t] = pmv ? acc[r] : NEGV;
                }
            }
        }
        return;
    }

    // ---------------------- lemma MX-fp8 dual GEMM ----------------------
    __shared__ unsigned char sA[128 * 128];    // 16 KB  [row][swizzled 16B unit]
    __shared__ unsigned char sBg[128 * 128];
    __shared__ unsigned char sBv[128 * 128];
    __shared__ float sRed[256];

    const int bx = blockIdx.x - NLM;
    const int wm = w & 1;
    const int wn = w >> 1;
    const int r8 = lane >> 3;
    const int c8 = lane & 7;
    const int g8 = c8 ^ r8;            // XOR swizzle (16B units)
    const int etile = bx * 128;

    int idS[4], idG[4];
#pragma unroll
    for (int i = 0; i < 4; i++) {
        int row = (i * 4 + w) * 8 + r8;
        int e = etile + row;
        idS[i] = (e < E) ? scope[e] : 0;
        idG[i] = (e < E) ? goal[e] : 0;
    }

    float lem[16];
#pragma unroll
    for (int i = 0; i < 16; i++) lem[i] = 0.f;

    for (int nt = 0; nt < NDIM / 128; nt++) {
        const int n0 = nt * 128;
        f32x4 accG[4][4], accV[4][4];
#pragma unroll
        for (int mi = 0; mi < 4; mi++)
#pragma unroll
            for (int ni = 0; ni < 4; ni++) {
                accG[mi][ni] = (f32x4){0.f, 0.f, 0.f, 0.f};
                accV[mi][ni] = (f32x4){0.f, 0.f, 0.f, 0.f};
            }
#pragma unroll
        for (int kc = 0; kc < 4; kc++) {
            const int k0 = kc * 128;           // byte offset in W^T fp8 row
            const int koff = (kc & 1) * 128;   // byte offset in tf8 row
            const bool useS = (kc < 2);
            __syncthreads();
#pragma unroll
            for (int i = 0; i < 4; i++) {
                const int chunk = i * 4 + w;
                int id = useS ? idS[i] : idG[i];
                gl2lds16(tf8 + (size_t)id * DDIM + koff + g8 * 16, &sA[chunk * 1024]);
                int rowB = chunk * 8 + r8;
                gl2lds16(wg8 + (size_t)(n0 + rowB) * KDIM + k0 + g8 * 16, &sBg[chunk * 1024]);
                gl2lds16(wv8 + (size_t)(n0 + rowB) * KDIM + k0 + g8 * 16, &sBv[chunk * 1024]);
            }
            __syncthreads();
            i32x8 af[4];
#pragma unroll
            for (int mi = 0; mi < 4; mi++) {
                int row = wm * 64 + mi * 16 + col;
                int r7 = row & 7;
                uint4 lo = *(const uint4*)(&sA[row * 128 + ((2 * q) ^ r7) * 16]);
                uint4 hi = *(const uint4*)(&sA[row * 128 + ((2 * q + 1) ^ r7) * 16]);
                af[mi] = (i32x8){(int)lo.x, (int)lo.y, (int)lo.z, (int)lo.w,
                                 (int)hi.x, (int)hi.y, (int)hi.z, (int)hi.w};
            }
#pragma unroll
            for (int ni = 0; ni < 4; ni++) {
                int row = wn * 64 + ni * 16 + col;
                int r7 = row & 7;
                uint4 lo = *(const uint4*)(&sBg[row * 128 + ((2 * q) ^ r7) * 16]);
                uint4 hi = *(const uint4*)(&sBg[row * 128 + ((2 * q + 1) ^ r7) * 16]);
                i32x8 bg = (i32x8){(int)lo.x, (int)lo.y, (int)lo.z, (int)lo.w,
                                   (int)hi.x, (int)hi.y, (int)hi.z, (int)hi.w};
                lo = *(const uint4*)(&sBv[row * 128 + ((2 * q) ^ r7) * 16]);
                hi = *(const uint4*)(&sBv[row * 128 + ((2 * q + 1) ^ r7) * 16]);
                i32x8 bv = (i32x8){(int)lo.x, (int)lo.y, (int)lo.z, (int)lo.w,
                                   (int)hi.x, (int)hi.y, (int)hi.z, (int)hi.w};
#pragma unroll
                for (int mi = 0; mi < 4; mi++) {
                    accG[mi][ni] = __builtin_amdgcn_mfma_scale_f32_16x16x128_f8f6f4(
                        af[mi], bg, accG[mi][ni], 0, 0, 0, 0x7F7F7F7F, 0, 0x7F7F7F7F);
                    accV[mi][ni] = __builtin_amdgcn_mfma_scale_f32_16x16x128_f8f6f4(
                        af[mi], bv, accV[mi][ni], 0, 0, 0, 0x7F7F7F7F, 0, 0x7F7F7F7F);
                }
            }
        }
        // epilogue: lem += silu(G) * V * Wo[n]. C/D: M=q*4+r, N=col.
#pragma unroll
        for (int ni = 0; ni < 4; ni++) {
            float wo = Wo[n0 + wn * 64 + ni * 16 + col];
#pragma unroll
            for (int mi = 0; mi < 4; mi++)
#pragma unroll
                for (int r = 0; r < 4; r++) {
                    float g = accG[mi][ni][r];
                    float v = accV[mi][ni][r];
                    float s = g / (1.f + __expf(-g));
                    lem[mi * 4 + r] += s * v * wo;
                }
        }
    }
#pragma unroll
    for (int i = 0; i < 16; i++) {
        float v = lem[i];
        for (int off = 8; off > 0; off >>= 1) v += __shfl_xor(v, off, 16);
        if (col == 0) {
            int row = wm * 64 + (i >> 2) * 16 + q * 4 + (i & 3);
            sRed[wn * 128 + row] = v;
        }
    }
    __syncthreads();
    if (tid < 128) {
        int e = etile + tid;
        if (e < E) outLem[e] = sRed[tid] + sRed[128 + tid];
    }
}

extern "C" void kernel_launch(void* const* d_in, const int* in_sizes, int n_in,
                              void* d_out, int out_size, void* d_ws, size_t ws_size,
                              hipStream_t stream) {
    const float* tok = (const float*)d_in[0];
    const float* Wg  = (const float*)d_in[1];
    const float* Wv  = (const float*)d_in[2];
    const float* Wo  = (const float*)d_in[3];
    const int* edge = (const int*)d_in[4];
    const int* lmi  = (const int*)d_in[5];
    const int* bp   = (const int*)d_in[6];
    const int* tpm  = (const int*)d_in[7];
    const int E = in_sizes[4] / 2;           // 100000
    float* out = (float*)d_out;

    // workspace layout (~13.2 MB)
    unsigned short* tfb = (unsigned short*)d_ws;                       // 8 MB
    unsigned char*  tf8 = (unsigned char*)(tfb + (size_t)NROWS * DDIM); // 4 MB
    unsigned char*  wg8 = tf8 + (size_t)NROWS * DDIM;                  // 512 KB
    unsigned char*  wv8 = wg8 + (size_t)NDIM * KDIM;                   // 512 KB
    int* counts = (int*)(wv8 + (size_t)NDIM * KDIM);                   // 128 B
    unsigned short* lists = (unsigned short*)(counts + 32);            // 128 KB

    prep_all<<<dim3(4609), dim3(256), 0, stream>>>(
        tok, Wg, Wv, bp, tfb, tf8, wg8, wv8, counts, lists);
    int nLemBlocks = (E + 127) / 128;        // 782
    fused_main<<<dim3(NLM + nLemBlocks), dim3(256), 0, stream>>>(
        tf8, wg8, wv8, Wo, edge, edge + E, out, E,
        tok, tfb, lmi, counts, lists, tpm, out + E);
}

// Round 7
// 268.274 us; speedup vs baseline: 3.8860x; 1.3794x over previous
//
#include <hip/hip_runtime.h>
#include <hip/hip_bf16.h>

typedef __bf16 bf16x8 __attribute__((ext_vector_type(8)));
typedef int   i32x8 __attribute__((ext_vector_type(8)));
typedef float f32x4 __attribute__((ext_vector_type(4)));

#define KDIM 512
#define NDIM 1024
#define DDIM 256
#define TDIM 512
#define MDIM 2048
#define NROWS 16384          // B*T type_flat rows
#define NEGV -1e10f
#define NLM 128              // lm blocks fused at the front of the main grid

__device__ __forceinline__ unsigned short f2b(float f) {
    unsigned int u = __builtin_bit_cast(unsigned int, f);
    u += 0x7fffu + ((u >> 16) & 1u);   // RNE
    return (unsigned short)(u >> 16);
}

typedef const __attribute__((address_space(1))) unsigned int* gas_p;
typedef __attribute__((address_space(3))) unsigned int* las_p;
__device__ __forceinline__ void gl2lds16(const void* g, void* l) {
    __builtin_amdgcn_global_load_lds((gas_p)g, (las_p)l, 16, 0, 0);
}

// ---------------------------------------------------------------------------
// prep_all: one launch, three roles by blockIdx.  (unchanged from R6)
// ---------------------------------------------------------------------------
__global__ void prep_all(const float* __restrict__ tok,
                         const float* __restrict__ Wg,
                         const float* __restrict__ Wv,
                         const int* __restrict__ bp,
                         unsigned short* __restrict__ tfb,
                         unsigned char* __restrict__ tf8,
                         unsigned char* __restrict__ wg8,
                         unsigned char* __restrict__ wv8,
                         int* __restrict__ counts,
                         unsigned short* __restrict__ lists) {
    const int bid = blockIdx.x;
    const int tid = threadIdx.x;
    if (bid < 4096) {
        int g = (bid * 256 + tid) * 4;
        int i = g >> 8, c = g & 255;
        float4 v = *(const float4*)(tok + (size_t)i * 1024 + c);
        tfb[g + 0] = f2b(v.x);
        tfb[g + 1] = f2b(v.y);
        tfb[g + 2] = f2b(v.z);
        tfb[g + 3] = f2b(v.w);
        unsigned int p = (unsigned int)__builtin_amdgcn_cvt_pk_fp8_f32(v.x, v.y, 0, 0);
        p = (unsigned int)__builtin_amdgcn_cvt_pk_fp8_f32(v.z, v.w, (int)p, 1);
        *(unsigned int*)(tf8 + g) = p;
    } else if (bid < 4608) {
        __shared__ float tg[32][33];
        __shared__ float tv[32][33];
        int pb = bid - 4096;
        int n0 = (pb & 31) * 32, k0 = (pb >> 5) * 32;
        {
            int kk = tid >> 3, nn = (tid & 7) * 4;
            float4 g = *(const float4*)(Wg + (size_t)(k0 + kk) * NDIM + n0 + nn);
            float4 v = *(const float4*)(Wv + (size_t)(k0 + kk) * NDIM + n0 + nn);
            tg[kk][nn] = g.x; tg[kk][nn + 1] = g.y; tg[kk][nn + 2] = g.z; tg[kk][nn + 3] = g.w;
            tv[kk][nn] = v.x; tv[kk][nn + 1] = v.y; tv[kk][nn + 2] = v.z; tv[kk][nn + 3] = v.w;
        }
        __syncthreads();
        int nn2 = tid >> 3, kk2 = (tid & 7) * 4;
        unsigned int pg = (unsigned int)__builtin_amdgcn_cvt_pk_fp8_f32(
            tg[kk2][nn2], tg[kk2 + 1][nn2], 0, 0);
        pg = (unsigned int)__builtin_amdgcn_cvt_pk_fp8_f32(
            tg[kk2 + 2][nn2], tg[kk2 + 3][nn2], (int)pg, 1);
        unsigned int pv = (unsigned int)__builtin_amdgcn_cvt_pk_fp8_f32(
            tv[kk2][nn2], tv[kk2 + 1][nn2], 0, 0);
        pv = (unsigned int)__builtin_amdgcn_cvt_pk_fp8_f32(
            tv[kk2 + 2][nn2], tv[kk2 + 3][nn2], (int)pv, 1);
        *(unsigned int*)(wg8 + (size_t)(n0 + nn2) * KDIM + k0 + kk2) = pg;
        *(unsigned int*)(wv8 + (size_t)(n0 + nn2) * KDIM + k0 + kk2) = pv;
    } else {
        __shared__ int c[32];
        if (tid < 32) c[tid] = 0;
        __syncthreads();
        for (int m = tid; m < MDIM; m += 256) {
            int b = bp[m];
            int pos = atomicAdd(&c[b], 1);
            lists[b * MDIM + pos] = (unsigned short)m;
        }
        __syncthreads();
        if (tid < 32) counts[tid] = c[tid];
    }
}

// ---------------------------------------------------------------------------
// fused_main: blocks [0,NLM) = lm_preds gather-GEMM (unchanged, proven);
// blocks [NLM,..) = lemma MX-fp8 dual GEMM, RESTRUCTURED:
//   - A (gathered edges, 128 rows x 512 B fp8) staged ONCE per block into
//     64 KB persistent LDS (was re-gathered 8x -> HBM L2-thrash)
//   - 16 n-tiles of 64; per (nt,kc) only a 16 KB L2-hot B-chunk is staged
//   - wave tile 64m x 32n dual-acc = 64 regs (was 128) -> no spill risk
//   - XOR source-swizzle: LDS position p holds unit p^(row&7) per 128B chunk
// LDS = 64 KB A + 16 KB B = exactly 80 KB -> 2 blocks/CU.
// ---------------------------------------------------------------------------
__launch_bounds__(256, 2)
__global__ void fused_main(const unsigned char* __restrict__ tf8,
                           const unsigned char* __restrict__ wg8,
                           const unsigned char* __restrict__ wv8,
                           const float* __restrict__ Wo,
                           const int* __restrict__ scope,
                           const int* __restrict__ goal,
                           float* __restrict__ outLem, int E,
                           const float* __restrict__ tok,
                           const unsigned short* __restrict__ tfb,
                           const int* __restrict__ lmi,
                           const int* __restrict__ counts,
                           const unsigned short* __restrict__ lists,
                           const int* __restrict__ tpm,
                           float* __restrict__ outP) {
    __shared__ unsigned char sA[128 * 512];   // 64 KB: seg = row*2+half, 256 B each
    __shared__ unsigned char sB[2 * 64 * 128]; // 16 KB: [arr][n_local][128]

    const int tid = threadIdx.x;
    const int lane = tid & 63;
    const int w = tid >> 6;
    const int col = lane & 15;
    const int q = lane >> 4;

    if ((int)blockIdx.x < NLM) {
        // ---------------- lm_preds gather-GEMM (R5/R6-proven) ----------------
        const int lb = blockIdx.x;
        const int b = lb & 31;
        const int t0 = (lb >> 5) * 128;
        const int cnt = counts[b];
        for (int mt = w * 16; mt < cnt; mt += 64) {
            int mc = mt + col;
            int aid = lists[b * MDIM + (mc < cnt ? mc : cnt - 1)];
            const float* arow = tok + (size_t)lmi[aid] * DDIM;
            bf16x8 af[8];
#pragma unroll
            for (int k = 0; k < 8; k++) {
                float4 lo = *(const float4*)(arow + k * 32 + q * 8);
                float4 hi = *(const float4*)(arow + k * 32 + q * 8 + 4);
                uint4 p;
                p.x = f2b(lo.x) | ((unsigned int)f2b(lo.y) << 16);
                p.y = f2b(lo.z) | ((unsigned int)f2b(lo.w) << 16);
                p.z = f2b(hi.x) | ((unsigned int)f2b(hi.y) << 16);
                p.w = f2b(hi.z) | ((unsigned int)f2b(hi.w) << 16);
                af[k] = __builtin_bit_cast(bf16x8, p);
            }
            int gm[4];
#pragma unroll
            for (int r = 0; r < 4; r++) {
                int mrow = mt + q * 4 + r;
                gm[r] = (mrow < cnt) ? (int)lists[b * MDIM + mrow] : -1;
            }
#pragma unroll
            for (int ntile = 0; ntile < 8; ntile++) {
                int t = t0 + ntile * 16 + col;
                const unsigned short* brow = tfb + (size_t)(b * TDIM + t) * DDIM;
                f32x4 acc = (f32x4){0.f, 0.f, 0.f, 0.f};
#pragma unroll
                for (int k = 0; k < 8; k++) {
                    bf16x8 bf = __builtin_bit_cast(bf16x8,
                        *(const uint4*)(brow + k * 32 + q * 8));
                    acc = __builtin_amdgcn_mfma_f32_16x16x32_bf16(af[k], bf, acc, 0, 0, 0);
                }
                int pmv = tpm[b * TDIM + t];
#pragma unroll
                for (int r = 0; r < 4; r++) {
                    if (gm[r] >= 0)
                        outP[(size_t)gm[r] * TDIM + t] = pmv ? acc[r] : NEGV;
                }
            }
        }
        return;
    }

    // ------------------------- lemma MX-fp8 GEMM -------------------------
    const int bx = blockIdx.x - NLM;
    const int etile = bx * 128;
    const int wm = w & 1;      // m-half (64 rows)
    const int wn = w >> 1;     // n-half (32 cols of the 64-wide n-tile)

    // ---- stage A once: 256 segments of 256 B; instr covers 4 segments ----
    // seg = row*2 + h  (h=0: scope row bytes, h=1: goal row bytes)
    // lane: seg = s0 + (lane>>4), unit u = lane&15; source unit swizzled
#pragma unroll
    for (int i = 0; i < 16; i++) {
        int s0 = i * 16 + w * 4;
        int seg = s0 + (lane >> 4);
        int row = seg >> 1;
        int h = seg & 1;
        int e = etile + row;
        int id = (e < E) ? (h ? goal[e] : scope[e]) : 0;
        int u = lane & 15;
        int usw = (u & 8) | ((u & 7) ^ (row & 7));
        gl2lds16(tf8 + (size_t)id * DDIM + usw * 16, &sA[s0 * 256]);
    }

    float lem[16];
#pragma unroll
    for (int i = 0; i < 16; i++) lem[i] = 0.f;

    for (int nt = 0; nt < 16; nt++) {
        const int n0 = nt * 64;
        f32x4 accG[4][2], accV[4][2];
#pragma unroll
        for (int mi = 0; mi < 4; mi++)
#pragma unroll
            for (int ni = 0; ni < 2; ni++) {
                accG[mi][ni] = (f32x4){0.f, 0.f, 0.f, 0.f};
                accV[mi][ni] = (f32x4){0.f, 0.f, 0.f, 0.f};
            }
#pragma unroll
        for (int kc = 0; kc < 4; kc++) {
            __syncthreads();
            // stage B chunk: 2 arrays x 64 rows x 128 B; 4 instrs/wave
#pragma unroll
            for (int a = 0; a < 2; a++)
#pragma unroll
                for (int j = 0; j < 2; j++) {
                    int rowL = w * 16 + j * 8 + (lane >> 3);
                    int u7 = (lane & 7) ^ (rowL & 7);
                    const unsigned char* src = (a ? wv8 : wg8) +
                        (size_t)(n0 + rowL) * KDIM + kc * 128 + u7 * 16;
                    gl2lds16(src, &sB[a * 8192 + (w * 16 + j * 8) * 128]);
                }
            __syncthreads();
            i32x8 af[4];
#pragma unroll
            for (int mi = 0; mi < 4; mi++) {
                int row = wm * 64 + mi * 16 + col;
                int r7 = row & 7;
                const unsigned char* base = &sA[row * 512 + (kc >> 1) * 256 + (kc & 1) * 128];
                uint4 lo = *(const uint4*)(base + (((2 * q) ^ r7) * 16));
                uint4 hi = *(const uint4*)(base + (((2 * q + 1) ^ r7) * 16));
                af[mi] = (i32x8){(int)lo.x, (int)lo.y, (int)lo.z, (int)lo.w,
                                 (int)hi.x, (int)hi.y, (int)hi.z, (int)hi.w};
            }
#pragma unroll
            for (int ni = 0; ni < 2; ni++) {
                int nl = wn * 32 + ni * 16 + col;
                int r7 = nl & 7;
                const unsigned char* bgp = &sB[nl * 128];
                uint4 lo = *(const uint4*)(bgp + (((2 * q) ^ r7) * 16));
                uint4 hi = *(const uint4*)(bgp + (((2 * q + 1) ^ r7) * 16));
                i32x8 bg = (i32x8){(int)lo.x, (int)lo.y, (int)lo.z, (int)lo.w,
                                   (int)hi.x, (int)hi.y, (int)hi.z, (int)hi.w};
                lo = *(const uint4*)(bgp + 8192 + (((2 * q) ^ r7) * 16));
                hi = *(const uint4*)(bgp + 8192 + (((2 * q + 1) ^ r7) * 16));
                i32x8 bv = (i32x8){(int)lo.x, (int)lo.y, (int)lo.z, (int)lo.w,
                                   (int)hi.x, (int)hi.y, (int)hi.z, (int)hi.w};
#pragma unroll
                for (int mi = 0; mi < 4; mi++) {
                    accG[mi][ni] = __builtin_amdgcn_mfma_scale_f32_16x16x128_f8f6f4(
                        af[mi], bg, accG[mi][ni], 0, 0, 0, 0x7F7F7F7F, 0, 0x7F7F7F7F);
                    accV[mi][ni] = __builtin_amdgcn_mfma_scale_f32_16x16x128_f8f6f4(
                        af[mi], bv, accV[mi][ni], 0, 0, 0, 0x7F7F7F7F, 0, 0x7F7F7F7F);
                }
            }
        }
        // epilogue: lem += silu(G) * V * Wo[n]. C/D: M=q*4+r, N=col.
#pragma unroll
        for (int ni = 0; ni < 2; ni++) {
            float wo = Wo[n0 + wn * 32 + ni * 16 + col];
#pragma unroll
            for (int mi = 0; mi < 4; mi++)
#pragma unroll
                for (int r = 0; r < 4; r++) {
                    float g = accG[mi][ni][r];
                    float v = accV[mi][ni][r];
                    float s = g / (1.f + __expf(-g));
                    lem[mi * 4 + r] += s * v * wo;
                }
        }
    }
    // reduce across 16 N-cols, then across the 2 n-waves (sRed aliases sB)
    __syncthreads();
    float* sRed = (float*)sB;
#pragma unroll
    for (int i = 0; i < 16; i++) {
        float v = lem[i];
        for (int off = 8; off > 0; off >>= 1) v += __shfl_xor(v, off, 16);
        if (col == 0) {
            int row = wm * 64 + (i >> 2) * 16 + q * 4 + (i & 3);
            sRed[wn * 128 + row] = v;
        }
    }
    __syncthreads();
    if (tid < 128) {
        int e = etile + tid;
        if (e < E) outLem[e] = sRed[tid] + sRed[128 + tid];
    }
}

extern "C" void kernel_launch(void* const* d_in, const int* in_sizes, int n_in,
                              void* d_out, int out_size, void* d_ws, size_t ws_size,
                              hipStream_t stream) {
    const float* tok = (const float*)d_in[0];
    const float* Wg  = (const float*)d_in[1];
    const float* Wv  = (const float*)d_in[2];
    const float* Wo  = (const float*)d_in[3];
    const int* edge = (const int*)d_in[4];
    const int* lmi  = (const int*)d_in[5];
    const int* bp   = (const int*)d_in[6];
    const int* tpm  = (const int*)d_in[7];
    const int E = in_sizes[4] / 2;           // 100000
    float* out = (float*)d_out;

    // workspace layout (~13.2 MB)
    unsigned short* tfb = (unsigned short*)d_ws;                        // 8 MB
    unsigned char*  tf8 = (unsigned char*)(tfb + (size_t)NROWS * DDIM); // 4 MB
    unsigned char*  wg8 = tf8 + (size_t)NROWS * DDIM;                   // 512 KB
    unsigned char*  wv8 = wg8 + (size_t)NDIM * KDIM;                    // 512 KB
    int* counts = (int*)(wv8 + (size_t)NDIM * KDIM);                    // 128 B
    unsigned short* lists = (unsigned short*)(counts + 32);             // 128 KB

    prep_all<<<dim3(4609), dim3(256), 0, stream>>>(
        tok, Wg, Wv, bp, tfb, tf8, wg8, wv8, counts, lists);
    int nLemBlocks = (E + 127) / 128;        // 782
    fused_main<<<dim3(NLM + nLemBlocks), dim3(256), 0, stream>>>(
        tf8, wg8, wv8, Wo, edge, edge + E, out, E,
        tok, tfb, lmi, counts, lists, tpm, out + E);
}